// Round 3
// baseline (17068.127 us; speedup 1.0000x reference)
//
#include <hip/hip_runtime.h>
#include <hip/hip_bf16.h>

#define Bsz 512
#define Tsz 128
#define Msz 512
#define Psz 512

typedef __attribute__((ext_vector_type(8))) unsigned short ushort8v;

__device__ __forceinline__ float bf2f(unsigned short u) {
    union { unsigned int i; float f; } c; c.i = ((unsigned int)u) << 16; return c.f;
}
__device__ __forceinline__ unsigned short f2bf(float f) {
    union { float f; unsigned int i; } c; c.f = f;
    unsigned int u = c.i;
    unsigned int r = u + 0x7fffu + ((u >> 16) & 1u);
    return (unsigned short)(r >> 16);
}
__device__ __forceinline__ float fast_tanh(float x) {
    x = fminf(fmaxf(x, -15.f), 15.f);
    float e = __expf(2.f * x);
    return 1.f - 2.f / (e + 1.f);
}
__device__ __forceinline__ float fast_sig(float x) {
    x = fminf(fmaxf(x, -30.f), 30.f);
    return 1.f / (1.f + __expf(-x));
}

// ---------------- Uy = encoded @ U^T, output bf16 ----------------
// A: [B*T, 512] f32, U: [512, 512] f32, C: [B*T, 512] bf16
__global__ __launch_bounds__(256) void k_uy(const float* __restrict__ A,
                                            const float* __restrict__ U,
                                            unsigned short* __restrict__ C) {
    __shared__ float As[32][68];  // [k][row]
    __shared__ float Us[32][68];  // [k][col]
    const int tid = threadIdx.x;
    const int tx = tid & 15, ty = tid >> 4;
    const size_t r0 = (size_t)blockIdx.y * 64;
    const int n0 = blockIdx.x * 64;
    float acc[4][4] = {};
    for (int k0 = 0; k0 < 512; k0 += 32) {
#pragma unroll
        for (int i = 0; i < 2; ++i) {
            int f = tid + i * 256;            // 0..511
            int r = f >> 3;                   // 0..63
            int kc = (f & 7) * 4;
            float4 v = *reinterpret_cast<const float4*>(&A[(r0 + r) * 512 + k0 + kc]);
            As[kc + 0][r] = v.x; As[kc + 1][r] = v.y; As[kc + 2][r] = v.z; As[kc + 3][r] = v.w;
            float4 w = *reinterpret_cast<const float4*>(&U[(size_t)(n0 + r) * 512 + k0 + kc]);
            Us[kc + 0][r] = w.x; Us[kc + 1][r] = w.y; Us[kc + 2][r] = w.z; Us[kc + 3][r] = w.w;
        }
        __syncthreads();
#pragma unroll
        for (int k = 0; k < 32; ++k) {
            float4 a = *reinterpret_cast<const float4*>(&As[k][ty * 4]);
            float4 b = *reinterpret_cast<const float4*>(&Us[k][tx * 4]);
            float av[4] = {a.x, a.y, a.z, a.w};
            float bv[4] = {b.x, b.y, b.z, b.w};
#pragma unroll
            for (int i = 0; i < 4; ++i)
#pragma unroll
                for (int j = 0; j < 4; ++j)
                    acc[i][j] = fmaf(av[i], bv[j], acc[i][j]);
        }
        __syncthreads();
    }
#pragma unroll
    for (int i = 0; i < 4; ++i) {
        size_t row = r0 + ty * 4 + i;
        ushort4 o;
        o.x = f2bf(acc[i][0]); o.y = f2bf(acc[i][1]);
        o.z = f2bf(acc[i][2]); o.w = f2bf(acc[i][3]);
        *reinterpret_cast<ushort4*>(&C[row * 512 + n0 + tx * 4]) = o;
    }
}

// ---------------- zero-init d, s ----------------
__global__ void k_zero(float* a, float* b, int n) {
    int i = blockIdx.x * blockDim.x + threadIdx.x;
    if (i < n) { a[i] = 0.f; b[i] = 0.f; }
}

// ---------------- x1 = [d,s] @ W_d_w^T + b ----------------
__global__ __launch_bounds__(256) void k_x1(const float* __restrict__ dcur,
                                            const float* __restrict__ scur,
                                            const float* __restrict__ Wd,
                                            const float* __restrict__ Wdb,
                                            float* __restrict__ x1) {
    __shared__ float Ds[32][36];
    __shared__ float Ws[32][36];
    const int tid = threadIdx.x;
    const int tx = tid & 15, ty = tid >> 4;
    const int m0 = blockIdx.x * 32, b0 = blockIdx.y * 32;
    float acc[2][2] = {};
    for (int k0 = 0; k0 < 1024; k0 += 32) {
        const float* src = (k0 < 512) ? dcur : scur;
        const int kb = k0 & 511;
        {
            int r = tid >> 3, kc = (tid & 7) * 4;
            float4 v = *reinterpret_cast<const float4*>(&src[(size_t)(b0 + r) * 512 + kb + kc]);
            Ds[kc + 0][r] = v.x; Ds[kc + 1][r] = v.y; Ds[kc + 2][r] = v.z; Ds[kc + 3][r] = v.w;
            float4 w = *reinterpret_cast<const float4*>(&Wd[(size_t)(m0 + r) * 1024 + k0 + kc]);
            Ws[kc + 0][r] = w.x; Ws[kc + 1][r] = w.y; Ws[kc + 2][r] = w.z; Ws[kc + 3][r] = w.w;
        }
        __syncthreads();
#pragma unroll
        for (int k = 0; k < 32; ++k) {
            float2 a = *reinterpret_cast<const float2*>(&Ds[k][ty * 2]);
            float2 b = *reinterpret_cast<const float2*>(&Ws[k][tx * 2]);
            acc[0][0] = fmaf(a.x, b.x, acc[0][0]);
            acc[0][1] = fmaf(a.x, b.y, acc[0][1]);
            acc[1][0] = fmaf(a.y, b.x, acc[1][0]);
            acc[1][1] = fmaf(a.y, b.y, acc[1][1]);
        }
        __syncthreads();
    }
#pragma unroll
    for (int i = 0; i < 2; ++i)
#pragma unroll
        for (int j = 0; j < 2; ++j) {
            int m = m0 + tx * 2 + j;
            x1[(size_t)(b0 + ty * 2 + i) * 512 + m] = acc[i][j] + Wdb[m];
        }
}

// ---------------- l[b,t] = sum_m tanh(x1+Uy)*v ----------------
__global__ __launch_bounds__(256) void k_logits(const unsigned short* __restrict__ Uyb,
                                                const float* __restrict__ x1,
                                                const float* __restrict__ vd,
                                                float* __restrict__ lout) {
    const int lane = threadIdx.x & 63;
    const int pair = blockIdx.x * 4 + (threadIdx.x >> 6);  // = b*128 + t
    const int b = pair >> 7;
    const unsigned short* uy = Uyb + (size_t)pair * 512 + lane * 8;
    const float* xp = x1 + (size_t)b * 512 + lane * 8;
    const float* vp = vd + lane * 8;
    ushort8v u = *reinterpret_cast<const ushort8v*>(uy);
    float4 x0 = *reinterpret_cast<const float4*>(xp);
    float4 x1v = *reinterpret_cast<const float4*>(xp + 4);
    float4 v0 = *reinterpret_cast<const float4*>(vp);
    float4 v1 = *reinterpret_cast<const float4*>(vp + 4);
    float acc;
    acc  = fast_tanh(bf2f(u[0]) + x0.x) * v0.x;
    acc += fast_tanh(bf2f(u[1]) + x0.y) * v0.y;
    acc += fast_tanh(bf2f(u[2]) + x0.z) * v0.z;
    acc += fast_tanh(bf2f(u[3]) + x0.w) * v0.w;
    acc += fast_tanh(bf2f(u[4]) + x1v.x) * v1.x;
    acc += fast_tanh(bf2f(u[5]) + x1v.y) * v1.y;
    acc += fast_tanh(bf2f(u[6]) + x1v.z) * v1.z;
    acc += fast_tanh(bf2f(u[7]) + x1v.w) * v1.w;
#pragma unroll
    for (int off = 32; off; off >>= 1) acc += __shfl_xor(acc, off);
    if (lane == 0) lout[pair] = acc;
}

// ---------------- softmax + c_t + y_tilda ----------------
__global__ __launch_bounds__(256) void k_smct(const float* __restrict__ lin,
                                              const float* __restrict__ enc,
                                              const float* __restrict__ wt,
                                              const float* __restrict__ wtb,
                                              const float* __restrict__ yin,
                                              float* __restrict__ cout,
                                              float* __restrict__ ytl, int tstep) {
    __shared__ float sb[128];
    __shared__ float sred[8];
    const int tid = threadIdx.x, b = blockIdx.x;
    if (tid < 128) sb[tid] = lin[b * 128 + tid];
    __syncthreads();
    if (tid < 64) {
        float v = fmaxf(sb[tid], sb[tid + 64]);
#pragma unroll
        for (int off = 32; off; off >>= 1) v = fmaxf(v, __shfl_xor(v, off));
        if (tid == 0) sred[0] = v;
    }
    __syncthreads();
    float mx = sred[0];
    if (tid < 128) sb[tid] = __expf(sb[tid] - mx);
    __syncthreads();
    if (tid < 64) {
        float v = sb[tid] + sb[tid + 64];
#pragma unroll
        for (int off = 32; off; off >>= 1) v += __shfl_xor(v, off);
        if (tid == 0) sred[1] = v;
    }
    __syncthreads();
    float inv = 1.f / sred[1];
    if (tid < 128) sb[tid] *= inv;
    __syncthreads();

    const float* eb = enc + (size_t)b * Tsz * Msz;
    float2 a = {0.f, 0.f};
#pragma unroll 4
    for (int t = 0; t < 128; ++t) {
        float bt = sb[t];
        float2 e = *reinterpret_cast<const float2*>(&eb[(size_t)t * 512 + tid * 2]);
        a.x = fmaf(bt, e.x, a.x);
        a.y = fmaf(bt, e.y, a.y);
    }
    *reinterpret_cast<float2*>(&cout[(size_t)b * 512 + tid * 2]) = a;
    float2 w2 = *reinterpret_cast<const float2*>(&wt[tid * 2]);
    float part = a.x * w2.x + a.y * w2.y;
#pragma unroll
    for (int off = 32; off; off >>= 1) part += __shfl_xor(part, off);
    const int lane = tid & 63, wid = tid >> 6;
    if (lane == 0) sred[2 + wid] = part;
    __syncthreads();
    if (tid == 0) {
        float s = sred[2] + sred[3] + sred[4] + sred[5];
        ytl[b] = s + yin[(size_t)b * 128 + tstep] * wt[512] + wtb[0];
    }
}

// ---------------- gates = yt*W_ih + d@W_hh^T + b; LSTM update ----------------
__global__ __launch_bounds__(256) void k_gates(const float* __restrict__ dcur,
                                               const float* __restrict__ scur,
                                               const float* __restrict__ Whh,
                                               const float* __restrict__ Wih,
                                               const float* __restrict__ bih,
                                               const float* __restrict__ bhh,
                                               const float* __restrict__ ytl,
                                               float* __restrict__ dnxt,
                                               float* __restrict__ snxt) {
    __shared__ float Ds[32][36];
    __shared__ float Ws[32][132];
    const int tid = threadIdx.x;
    const int tx = tid & 15, ty = tid >> 4;
    const int p0 = blockIdx.x * 32, b0 = blockIdx.y * 32;
    float acc[2][2][4] = {};
    for (int k0 = 0; k0 < 512; k0 += 32) {
        {
            int r = tid >> 3, kc = (tid & 7) * 4;
            float4 v = *reinterpret_cast<const float4*>(&dcur[(size_t)(b0 + r) * 512 + k0 + kc]);
            Ds[kc + 0][r] = v.x; Ds[kc + 1][r] = v.y; Ds[kc + 2][r] = v.z; Ds[kc + 3][r] = v.w;
        }
#pragma unroll
        for (int i = 0; i < 4; ++i) {
            int f = tid + i * 256;
            int row = f >> 3, kc = (f & 7) * 4;
            int g = row >> 5, pc = row & 31;
            float4 w = *reinterpret_cast<const float4*>(&Whh[(size_t)(g * 512 + p0 + pc) * 512 + k0 + kc]);
            Ws[kc + 0][row] = w.x; Ws[kc + 1][row] = w.y; Ws[kc + 2][row] = w.z; Ws[kc + 3][row] = w.w;
        }
        __syncthreads();
#pragma unroll
        for (int k = 0; k < 32; ++k) {
            float2 a = *reinterpret_cast<const float2*>(&Ds[k][ty * 2]);
            float2 w0 = *reinterpret_cast<const float2*>(&Ws[k][tx * 2]);
            float2 w1 = *reinterpret_cast<const float2*>(&Ws[k][32 + tx * 2]);
            float2 w2 = *reinterpret_cast<const float2*>(&Ws[k][64 + tx * 2]);
            float2 w3 = *reinterpret_cast<const float2*>(&Ws[k][96 + tx * 2]);
            acc[0][0][0] = fmaf(a.x, w0.x, acc[0][0][0]);
            acc[0][1][0] = fmaf(a.x, w0.y, acc[0][1][0]);
            acc[1][0][0] = fmaf(a.y, w0.x, acc[1][0][0]);
            acc[1][1][0] = fmaf(a.y, w0.y, acc[1][1][0]);
            acc[0][0][1] = fmaf(a.x, w1.x, acc[0][0][1]);
            acc[0][1][1] = fmaf(a.x, w1.y, acc[0][1][1]);
            acc[1][0][1] = fmaf(a.y, w1.x, acc[1][0][1]);
            acc[1][1][1] = fmaf(a.y, w1.y, acc[1][1][1]);
            acc[0][0][2] = fmaf(a.x, w2.x, acc[0][0][2]);
            acc[0][1][2] = fmaf(a.x, w2.y, acc[0][1][2]);
            acc[1][0][2] = fmaf(a.y, w2.x, acc[1][0][2]);
            acc[1][1][2] = fmaf(a.y, w2.y, acc[1][1][2]);
            acc[0][0][3] = fmaf(a.x, w3.x, acc[0][0][3]);
            acc[0][1][3] = fmaf(a.x, w3.y, acc[0][1][3]);
            acc[1][0][3] = fmaf(a.y, w3.x, acc[1][0][3]);
            acc[1][1][3] = fmaf(a.y, w3.y, acc[1][1][3]);
        }
        __syncthreads();
    }
#pragma unroll
    for (int bi = 0; bi < 2; ++bi)
#pragma unroll
        for (int pj = 0; pj < 2; ++pj) {
            int b = b0 + ty * 2 + bi, p = p0 + tx * 2 + pj;
            float yt = ytl[b];
            float gi = acc[bi][pj][0] + yt * Wih[p] + bih[p] + bhh[p];
            float gf = acc[bi][pj][1] + yt * Wih[512 + p] + bih[512 + p] + bhh[512 + p];
            float gg = acc[bi][pj][2] + yt * Wih[1024 + p] + bih[1024 + p] + bhh[1024 + p];
            float go = acc[bi][pj][3] + yt * Wih[1536 + p] + bih[1536 + p] + bhh[1536 + p];
            float sv = fast_sig(gf) * scur[(size_t)b * 512 + p] + fast_sig(gi) * fast_tanh(gg);
            snxt[(size_t)b * 512 + p] = sv;
            dnxt[(size_t)b * 512 + p] = fast_sig(go) * fast_tanh(sv);
        }
}

// ---------------- final: out = (concat(d,c)@W_y^T + b) @ v_y^T + vb ----------------
__global__ __launch_bounds__(256) void k_final(const float* __restrict__ dfin,
                                               const float* __restrict__ cfin,
                                               const float* __restrict__ Wy,
                                               const float* __restrict__ Wyb,
                                               const float* __restrict__ vy,
                                               const float* __restrict__ vyb,
                                               float* __restrict__ out) {
    __shared__ float hc[1024];
    __shared__ float sred[8];
    const int tid = threadIdx.x, b = blockIdx.x;
    hc[tid] = dfin[(size_t)b * 512 + tid];
    hc[256 + tid] = dfin[(size_t)b * 512 + 256 + tid];
    hc[512 + tid] = cfin[(size_t)b * 512 + tid];
    hc[768 + tid] = cfin[(size_t)b * 512 + 256 + tid];
    __syncthreads();
    float part = 0.f;
#pragma unroll
    for (int pi = 0; pi < 2; ++pi) {
        int p = tid + pi * 256;
        float acc = Wyb[p];
        const float* wr = Wy + (size_t)p * 1024;
#pragma unroll 4
        for (int k = 0; k < 1024; k += 4) {
            float4 w = *reinterpret_cast<const float4*>(&wr[k]);
            acc = fmaf(hc[k], w.x, acc);
            acc = fmaf(hc[k + 1], w.y, acc);
            acc = fmaf(hc[k + 2], w.z, acc);
            acc = fmaf(hc[k + 3], w.w, acc);
        }
        part += acc * vy[p];
    }
#pragma unroll
    for (int off = 32; off; off >>= 1) part += __shfl_xor(part, off);
    const int lane = tid & 63, wid = tid >> 6;
    if (lane == 0) sred[wid] = part;
    __syncthreads();
    if (tid == 0) out[b] = sred[0] + sred[1] + sred[2] + sred[3] + vyb[0];
}

extern "C" void kernel_launch(void* const* d_in, const int* in_sizes, int n_in,
                              void* d_out, int out_size, void* d_ws, size_t ws_size,
                              hipStream_t stream) {
    const float* enc = (const float*)d_in[0];
    const float* yin = (const float*)d_in[1];
    const float* Wdw = (const float*)d_in[2];
    const float* Wdb = (const float*)d_in[3];
    const float* Udw = (const float*)d_in[4];
    const float* vdw = (const float*)d_in[5];
    const float* wtw = (const float*)d_in[6];
    const float* wtb = (const float*)d_in[7];
    const float* Wyw = (const float*)d_in[8];
    const float* Wyb = (const float*)d_in[9];
    const float* vyw = (const float*)d_in[10];
    const float* vyb = (const float*)d_in[11];
    const float* Wih = (const float*)d_in[12];
    const float* Whh = (const float*)d_in[13];
    const float* bih = (const float*)d_in[14];
    const float* bhh = (const float*)d_in[15];
    float* out = (float*)d_out;

    // workspace layout
    unsigned short* Uyb = (unsigned short*)d_ws;                        // B*T*M bf16 = 64 MiB
    float* fb = (float*)((char*)d_ws + (size_t)Bsz * Tsz * Msz * 2);
    float* dbuf = fb;                     // 2 * B*P
    float* sbuf = dbuf + 2 * Bsz * Psz;   // 2 * B*P
    float* x1b  = sbuf + 2 * Bsz * Psz;   // B*M
    float* lb   = x1b + Bsz * Msz;        // B*T
    float* cb   = lb + Bsz * Tsz;         // B*M
    float* ytl  = cb + Bsz * Msz;         // B

    k_uy<<<dim3(Msz / 64, (Bsz * Tsz) / 64), 256, 0, stream>>>(enc, Udw, Uyb);
    k_zero<<<(Bsz * Psz + 255) / 256, 256, 0, stream>>>(dbuf, sbuf, Bsz * Psz);

    for (int t = 0; t < Tsz; ++t) {
        float* dc = dbuf + (t & 1) * (Bsz * Psz);
        float* sc = sbuf + (t & 1) * (Bsz * Psz);
        float* dn = dbuf + ((t & 1) ^ 1) * (Bsz * Psz);
        float* sn = sbuf + ((t & 1) ^ 1) * (Bsz * Psz);
        k_x1<<<dim3(16, 16), 256, 0, stream>>>(dc, sc, Wdw, Wdb, x1b);
        k_logits<<<(Bsz * Tsz) / 4, 256, 0, stream>>>(Uyb, x1b, vdw, lb);
        k_smct<<<Bsz, 256, 0, stream>>>(lb, enc, wtw, wtb, yin, cb, ytl, t);
        k_gates<<<dim3(16, 16), 256, 0, stream>>>(dc, sc, Whh, Wih, bih, bhh, ytl, dn, sn);
    }
    // after 128 steps the live buffers are parity 0
    k_final<<<Bsz, 256, 0, stream>>>(dbuf, cb, Wyw, Wyb, vyw, vyb, out);
}